// Round 1
// baseline (94.102 us; speedup 1.0000x reference)
//
#include <hip/hip_runtime.h>
#include <stdint.h>

#define IN_F 4096
#define OUT_F 11008
#define M_ROWS 256
#define RANK 16
#define NWORDS (IN_F / 16)   // 256 packed words per output row

#define BM 128
#define BN 64
#define BK 64
#define KT_COUNT (IN_F / BK) // 64

typedef unsigned short u16;
typedef __attribute__((ext_vector_type(8))) short short8;
typedef __attribute__((ext_vector_type(4))) float floatx4;

__device__ __forceinline__ u16 f32_to_bf16_rne(float f) {
    uint32_t u = __builtin_bit_cast(uint32_t, f);
    uint32_t r = (u + 0x7FFFu + ((u >> 16) & 1u)) >> 16;
    return (u16)r;
}

// ---------------- prep: rowsum, lora_xA, x->bf16 ----------------
__global__ __launch_bounds__(256) void prep_kernel(
    const float* __restrict__ x, const float* __restrict__ lora_A,
    u16* __restrict__ xb, float* __restrict__ srow, float* __restrict__ lxa)
{
    int m = blockIdx.x;
    int tid = threadIdx.x;
    const float* xrow = x + (size_t)m * IN_F;
    float ssum = 0.f;
    float acc[RANK];
#pragma unroll
    for (int r = 0; r < RANK; ++r) acc[r] = 0.f;
#pragma unroll
    for (int t = 0; t < IN_F / 256; ++t) {
        int i = t * 256 + tid;
        float v = xrow[i];
        ssum += v;
        xb[(size_t)m * IN_F + i] = f32_to_bf16_rne(v);
#pragma unroll
        for (int r = 0; r < RANK; ++r)
            acc[r] = fmaf(v, lora_A[r * IN_F + i], acc[r]);
    }
#pragma unroll
    for (int off = 32; off > 0; off >>= 1) {
        ssum += __shfl_down(ssum, off, 64);
#pragma unroll
        for (int r = 0; r < RANK; ++r) acc[r] += __shfl_down(acc[r], off, 64);
    }
    __shared__ float red[4][RANK + 1];
    int wv = tid >> 6, ln = tid & 63;
    if (ln == 0) {
        red[wv][0] = ssum;
#pragma unroll
        for (int r = 0; r < RANK; ++r) red[wv][1 + r] = acc[r];
    }
    __syncthreads();
    if (tid == 0) srow[m] = red[0][0] + red[1][0] + red[2][0] + red[3][0];
    if (tid < RANK)
        lxa[m * RANK + tid] = red[0][1 + tid] + red[1][1 + tid] + red[2][1 + tid] + red[3][1 + tid];
}

// ---------------- ternary decode: 8 x 2-bit codes -> 8 bf16 ----------------
// code c: 0 -> -1 (0xBF80), 1 -> 0 (0x0000), 2 -> +1 (0x3F80)
__device__ __forceinline__ short8 decode8(uint32_t h)
{
    uint32_t selA = (h & 0xFu) | ((h & 0xF0u) << 12);
    selA = (selA | (selA << 6)) & 0x03030303u;
    uint32_t h2 = h >> 8;
    uint32_t selB = (h2 & 0xFu) | ((h2 & 0xF0u) << 12);
    selB = (selB | (selB << 6)) & 0x03030303u;
    uint32_t hiA = __builtin_amdgcn_perm(0u, 0x003F00BFu, selA); // hi bytes
    uint32_t loA = __builtin_amdgcn_perm(0u, 0x00800080u, selA); // lo bytes
    uint32_t hiB = __builtin_amdgcn_perm(0u, 0x003F00BFu, selB);
    uint32_t loB = __builtin_amdgcn_perm(0u, 0x00800080u, selB);
    union { uint32_t u[4]; short8 s; } cvt;
    cvt.u[0] = __builtin_amdgcn_perm(hiA, loA, 0x05010400u);
    cvt.u[1] = __builtin_amdgcn_perm(hiA, loA, 0x07030602u);
    cvt.u[2] = __builtin_amdgcn_perm(hiB, loB, 0x05010400u);
    cvt.u[3] = __builtin_amdgcn_perm(hiB, loB, 0x07030602u);
    return cvt.s;
}

// ---------------- main fused GEMM ----------------
__global__ __launch_bounds__(256) void gemm_kernel(
    const u16* __restrict__ xb, const uint32_t* __restrict__ Tp,
    const float* __restrict__ alpha, const float* __restrict__ mu,
    const float* __restrict__ bias, const float* __restrict__ lora_B,
    const float* __restrict__ srow, const float* __restrict__ lxa,
    float* __restrict__ out)
{
    __shared__ __align__(16) u16 lds[2][BM * BK];
    const int tid = threadIdx.x;
    const int lane = tid & 63;
    const int wave = tid >> 6;
    const int wm = wave >> 1, wn = wave & 1;
    const int mb = blockIdx.y * BM;
    const int nb = blockIdx.x * BN;

    // B (ternary) addressing: lane holds T[brow][k0 + 8*(lane>>4) + j]
    const int brow0 = nb + wn * 32 + (lane & 15);
    const int bwsel = (lane >> 5);              // which word within 32-k step
    const int bshift = ((lane >> 4) & 1) * 16;  // which 16-bit half
    const uint32_t* tp0 = Tp + (size_t)brow0 * NWORDS + bwsel;
    const uint32_t* tp1 = Tp + (size_t)(brow0 + 16) * NWORDS + bwsel;

    floatx4 acc[4][2] = {};

    // A-read addressing (row low bits constant across mt since 16 % 8 == 0)
    const int r0 = wm * 64 + (lane & 15);
    const int rxor = r0 & 7;

    // ---- staging: global bf16 x tile -> LDS, pre-swizzled source ----
    auto stage = [&](int buf, int kt) {
        const int k0 = kt * BK;
#pragma unroll
        for (int j = 0; j < 4; ++j) {
            int q = (wave * 4 + j) * 64 + lane;   // 16B chunk id, 0..1023
            int row = q >> 3;                     // 8 chunks per 64-elem row
            int cc = q & 7;
            int scc = cc ^ (row & 7);             // inverse-swizzled source
            const u16* src = xb + (size_t)(mb + row) * IN_F + k0 + scc * 8;
            __builtin_amdgcn_global_load_lds(
                (const __attribute__((address_space(1))) void*)src,
                (__attribute__((address_space(3))) void*)(&lds[buf][(wave * 4 + j) * 512]),
                16, 0, 0);
        }
    };

    // prefetch B words for kt=0
    uint32_t bw[2][2];
#pragma unroll
    for (int kk = 0; kk < 2; ++kk) {
        bw[kk][0] = tp0[kk * 2];
        bw[kk][1] = tp1[kk * 2];
    }

    stage(0, 0);
    __syncthreads();

    for (int kt = 0; kt < KT_COUNT; ++kt) {
        const int cur = kt & 1;
        uint32_t nw[2][2] = {{0u, 0u}, {0u, 0u}};
        if (kt + 1 < KT_COUNT) {
#pragma unroll
            for (int kk = 0; kk < 2; ++kk) {
                nw[kk][0] = tp0[(kt + 1) * 4 + kk * 2];
                nw[kk][1] = tp1[(kt + 1) * 4 + kk * 2];
            }
            stage(cur ^ 1, kt + 1);
        }
#pragma unroll
        for (int kk = 0; kk < 2; ++kk) {
            short8 bfrag0 = decode8((bw[kk][0] >> bshift) & 0xFFFFu);
            short8 bfrag1 = decode8((bw[kk][1] >> bshift) & 0xFFFFu);
#pragma unroll
            for (int mt = 0; mt < 4; ++mt) {
                int row = r0 + mt * 16;
                int sc = (kk * 4 + (lane >> 4)) ^ rxor;
                const short8 afrag = *(const short8*)&lds[cur][row * BK + sc * 8];
                acc[mt][0] = __builtin_amdgcn_mfma_f32_16x16x32_bf16(afrag, bfrag0, acc[mt][0], 0, 0, 0);
                acc[mt][1] = __builtin_amdgcn_mfma_f32_16x16x32_bf16(afrag, bfrag1, acc[mt][1], 0, 0, 0);
            }
        }
#pragma unroll
        for (int kk = 0; kk < 2; ++kk) {
            bw[kk][0] = nw[kk][0];
            bw[kk][1] = nw[kk][1];
        }
        __syncthreads();
    }

    // ---- epilogue: alpha, mu*rowsum, 2*lora, bias ----
    const int o_base = nb + wn * 32 + (lane & 15);
    const int m_base = mb + wm * 64 + ((lane >> 4) * 4);

    float al[2], muv[2], bi[2], Brow[2][RANK];
#pragma unroll
    for (int nt = 0; nt < 2; ++nt) {
        int o = o_base + nt * 16;
        al[nt] = alpha[o];
        muv[nt] = mu[o];
        bi[nt] = bias[o];
#pragma unroll
        for (int r = 0; r < RANK; ++r) Brow[nt][r] = lora_B[o * RANK + r];
    }
#pragma unroll
    for (int mt = 0; mt < 4; ++mt) {
#pragma unroll
        for (int rg = 0; rg < 4; ++rg) {
            int m = m_base + mt * 16 + rg;
            float sm = srow[m];
            float lx[RANK];
#pragma unroll
            for (int r = 0; r < RANK; ++r) lx[r] = lxa[m * RANK + r];
#pragma unroll
            for (int nt = 0; nt < 2; ++nt) {
                float lora = 0.f;
#pragma unroll
                for (int r = 0; r < RANK; ++r) lora = fmaf(lx[r], Brow[nt][r], lora);
                out[(size_t)m * OUT_F + (o_base + nt * 16)] =
                    al[nt] * acc[mt][nt][rg] + muv[nt] * sm + 2.0f * lora + bi[nt];
            }
        }
    }
}

extern "C" void kernel_launch(void* const* d_in, const int* in_sizes, int n_in,
                              void* d_out, int out_size, void* d_ws, size_t ws_size,
                              hipStream_t stream)
{
    const float* x = (const float*)d_in[0];
    const uint32_t* Tp = (const uint32_t*)d_in[1];
    const float* alpha = (const float*)d_in[2];
    const float* mu = (const float*)d_in[3];
    const float* bias = (const float*)d_in[4];
    const float* lora_A = (const float*)d_in[5];
    const float* lora_B = (const float*)d_in[6];
    float* out = (float*)d_out;

    u16* xb = (u16*)d_ws;
    float* srow = (float*)((char*)d_ws + (size_t)M_ROWS * IN_F * 2);
    float* lxa = (float*)((char*)d_ws + (size_t)M_ROWS * IN_F * 2 + 1024);

    prep_kernel<<<dim3(M_ROWS), dim3(256), 0, stream>>>(x, lora_A, xb, srow, lxa);
    gemm_kernel<<<dim3(OUT_F / BN, M_ROWS / BM), dim3(256), 0, stream>>>(
        xb, Tp, alpha, mu, bias, lora_B, srow, lxa, out);
}